// Round 9
// baseline (236.047 us; speedup 1.0000x reference)
//
#include <hip/hip_runtime.h>
#include <math.h>

#define B_ 64
#define IC 2048
#define OC 32
#define OD 16
#define ID 8

#define GLOAD_LDS16(gp, lp)                                                       \
  __builtin_amdgcn_global_load_lds((const __attribute__((address_space(1))) void*)(gp), \
                                   (__attribute__((address_space(3))) void*)(lp), \
                                   16, 0, 0)

__device__ __forceinline__ float dot8(const float4 w0, const float4 w1,
                                      const float4 xa, const float4 xb) {
  return w0.x*xa.x + w0.y*xa.y + w0.z*xa.z + w0.w*xa.w
       + w1.x*xb.x + w1.y*xb.y + w1.z*xb.z + w1.w*xb.w;
}

// ---------------------------------------------------------------------------
// Fused routing pass (b_k = u.(v1+...+vk) algebra; unnormalized p=exp(u.vs),
// Z applied in reduceSquash).
//
// R9 geometry: grid = NCH (one block per i-chunk, 1 block/CU at NCH=256),
// block = 512 threads = 8 waves. Wave wv owns b in [wv*8, wv*8+8) (B_t=8).
// Lane: op=lane>>2, dq=lane&3; thread owns o in {op, op+16} (O_t=2) and
// d in [dq*4, dq*4+4).
// Per wave-iter: 16 W ds_read_b128 (= W[i] exactly once per wave, the
// provable minimum) + 16 x broadcast reads for 1024 wave-FMAs ->
// b128/FMA = 0.0625, half of R8; cross-wave W duplication 8x -> was 32x.
//
// W[i] (16KB) double-buffered via global_load_lds, source XOR-swizzled
// (involution p -> (p&~7)|((p&7)^((p>>3)&7))) so each thread's 8-f4 read
// per o2 spreads across all 32 banks (read index r ^ (lane&7)).
// x window [8 i][64 b][8 m] (16KB) staged once per 8-i subwindow.
// All blocks read disjoint W/x slices: pure streaming, no XCD remap needed.
// ---------------------------------------------------------------------------
template<bool WEIGHTED, int NCH>
__global__ __launch_bounds__(512, 2) void fusedK(
    const float* __restrict__ x, const float* __restrict__ W,
    const float* __restrict__ vs, float* __restrict__ part,
    float* __restrict__ zpart)
{
  constexpr int CI  = IC / NCH;
  constexpr int NSW = CI / 8;
  const int t    = threadIdx.x;
  const int ch   = blockIdx.x;
  const int lane = t & 63;
  const int wv   = t >> 6;
  const int op   = lane >> 2;
  const int dq   = lane & 3;
  const int rot  = lane & 7;
  const int i0   = ch * CI;
  const int b0   = wv * 8;             // wave's first b

  __shared__ float Wbuf[2][4096];      // 2 x 16 KB
  __shared__ float xall[1024 * 4];     // [8 i][64 b][8 m] = 16 KB

  const float4* Wg = (const float4*)W;
  const float4* xg = (const float4*)x;

  float4 acc[2][8];
  float  zacc[2][8];
  float4 vreg[2][8];
#pragma unroll
  for (int o2 = 0; o2 < 2; ++o2)
#pragma unroll
    for (int bb = 0; bb < 8; ++bb) {
      acc[o2][bb] = make_float4(0, 0, 0, 0);
      zacc[o2][bb] = 0.f;
    }

  if constexpr (WEIGHTED) {
#pragma unroll
    for (int o2 = 0; o2 < 2; ++o2)
#pragma unroll
      for (int bb = 0; bb < 8; ++bb)
        vreg[o2][bb] = *(const float4*)(
            vs + ((size_t)(b0 + bb) * 32 + op + o2 * 16) * 16 + dq * 4);
  }

  auto stageW = [&](int i, int nb) {
    const float4* Wi = Wg + (size_t)i * 1024;
#pragma unroll
    for (int k = 0; k < 2; ++k) {
      const int p   = k * 512 + t;
      const int src = (p & ~7) | ((p & 7) ^ ((p >> 3) & 7));
      GLOAD_LDS16(Wi + src, &Wbuf[nb][(k * 512 + wv * 64) * 4]);
    }
  };

  auto stageX = [&](int sw) {
    // xall f4 index p: i = p>>7, b = (p>>1)&63, h = p&1; linear dest
#pragma unroll
    for (int k = 0; k < 2; ++k) {
      const int p = k * 512 + t;
      const int i = p >> 7, b = (p >> 1) & 63, h = p & 1;
      GLOAD_LDS16(xg + ((size_t)b * IC + i0 + sw * 8 + i) * 2 + h,
                  &xall[(k * 512 + wv * 64) * 4]);
    }
  };

  stageX(0);
  stageW(i0, 0);
  int cur = 0;

#pragma unroll 1
  for (int sw = 0; sw < NSW; ++sw) {
#pragma unroll 1
    for (int j = 0; j < 8; ++j) {
      const int ii = sw * 8 + j;

      __syncthreads();                          // drains stage issued last iter
      if (ii + 1 < CI) stageW(i0 + ii + 1, cur ^ 1);

      // Full W fragment for both o-halves: W[i] read exactly once per wave.
      const float* Wb = &Wbuf[cur][0];
      float4 wr[2][8];
#pragma unroll
      for (int o2 = 0; o2 < 2; ++o2) {
        const int jb = (op + o2 * 16) * 32 + dq * 8;
#pragma unroll
        for (int r = 0; r < 8; ++r)
          wr[o2][r] = *(const float4*)&Wb[(jb + (r ^ rot)) * 4];
      }

#pragma unroll
      for (int bb = 0; bb < 8; ++bb) {
        const float* xp = &xall[(j * 128 + (b0 + bb) * 2) * 4];
        const float4 xa = *(const float4*)xp;        // wave-wide broadcast
        const float4 xc = *(const float4*)(xp + 4);  // wave-wide broadcast
#pragma unroll
        for (int o2 = 0; o2 < 2; ++o2) {
          float4 u;
          u.x = dot8(wr[o2][0], wr[o2][1], xa, xc);
          u.y = dot8(wr[o2][2], wr[o2][3], xa, xc);
          u.z = dot8(wr[o2][4], wr[o2][5], xa, xc);
          u.w = dot8(wr[o2][6], wr[o2][7], xa, xc);
          if constexpr (!WEIGHTED) {
            acc[o2][bb].x += u.x; acc[o2][bb].y += u.y;
            acc[o2][bb].z += u.z; acc[o2][bb].w += u.w;
          } else {
            const float4 vv = vreg[o2][bb];
            float pd = u.x * vv.x + u.y * vv.y + u.z * vv.z + u.w * vv.w;
            pd += __shfl_xor(pd, 1);          // reduce over dq (lane bits 0-1)
            pd += __shfl_xor(pd, 2);
            const float p = __expf(pd);       // unnormalized c
            acc[o2][bb].x = fmaf(p, u.x, acc[o2][bb].x);
            acc[o2][bb].y = fmaf(p, u.y, acc[o2][bb].y);
            acc[o2][bb].z = fmaf(p, u.z, acc[o2][bb].z);
            acc[o2][bb].w = fmaf(p, u.w, acc[o2][bb].w);
            zacc[o2][bb] += p;
          }
        }
      }
      cur ^= 1;
    }
    if (sw + 1 < NSW) {
      __syncthreads();              // all waves done reading xall window
      stageX(sw + 1);               // drained by next top-of-iteration barrier
    }
  }

  // epilogue: part[ch][b][o][d] f4-coalesced; zpart[ch][b*32+o] (dq==0)
  float4* part4 = (float4*)part;
#pragma unroll
  for (int o2 = 0; o2 < 2; ++o2)
#pragma unroll
    for (int bb = 0; bb < 8; ++bb) {
      const int b = b0 + bb;
      const int o = op + o2 * 16;
      part4[((size_t)ch * 64 + b) * 128 + o * 4 + dq] = acc[o2][bb];
      if constexpr (WEIGHTED) {
        if (dq == 0) zpart[(size_t)ch * 2048 + b * 32 + o] = zacc[o2][bb];
      }
    }
}

// ---------------------------------------------------------------------------
// Reduce s partials over chunks, normalize, squash.
// PASS 0: s*=1/2048, vs[g]  = v ; PASS 1: s*=rz, vs[g] += v ;
// PASS 2: s*=rz, out[g] = v.   grid 128 x 256; g = b*512 + o*16 + d.
// ---------------------------------------------------------------------------
template<int PASS, int NCH>
__global__ __launch_bounds__(256) void reduceSquash(
    const float* __restrict__ part, const float* __restrict__ rz,
    float* __restrict__ vsio, float* __restrict__ out)
{
  const int g = blockIdx.x * 256 + threadIdx.x;
  float s = 0.f;
#pragma unroll 8
  for (int ch = 0; ch < NCH; ++ch) s += part[(size_t)ch * 32768 + g];
  if constexpr (PASS == 0) s *= (1.f / 2048.f);
  else                     s *= rz[g >> 4];

  float sq = s * s;
#pragma unroll
  for (int k = 1; k < 16; k <<= 1) sq += __shfl_xor(sq, k);   // sum over d
  const float f = (sq / (1.f + sq)) * rsqrtf(sq + 1e-9f);
  const float v = s * f;

  if constexpr (PASS == 0)      vsio[g] = v;
  else if constexpr (PASS == 1) vsio[g] += v;
  else                          out[g] = v;
}

// ---------------------------------------------------------------------------
// Z reduction: rz[b*32+o] = 1 / sum_ch zpart. grid 8 x 256.
// ---------------------------------------------------------------------------
template<int NCH>
__global__ __launch_bounds__(256) void zredK(
    const float* __restrict__ zpart, float* __restrict__ rz)
{
  const int j = blockIdx.x * 256 + threadIdx.x;
  float zs = 0.f;
#pragma unroll 8
  for (int ch = 0; ch < NCH; ++ch) zs += zpart[(size_t)ch * 2048 + j];
  rz[j] = 1.f / zs;
}

// ---------------------------------------------------------------------------
extern "C" void kernel_launch(void* const* d_in, const int* in_sizes, int n_in,
                              void* d_out, int out_size, void* d_ws, size_t ws_size,
                              hipStream_t stream) {
  (void)in_sizes; (void)n_in; (void)out_size;
  const float* x = (const float*)d_in[0];
  const float* W = (const float*)d_in[1];
  float* out = (float*)d_out;
  float* ws  = (float*)d_ws;

  auto run = [&](auto tag) {
    constexpr int NCH = decltype(tag)::value;
    float* part  = ws;                                 // [NCH][64][32][16]
    float* zpart = part + (size_t)NCH * 32768;         // [NCH][2048]
    float* rz    = zpart + (size_t)NCH * 2048;         // [2048]
    float* vsb   = rz + 2048;                          // vs running sum [32768]

    const dim3 gF(NCH), bF(512), b256(256), gR(128);
    // pass 1: uniform c -> v1 (vs = v1)
    fusedK<false, NCH><<<gF, bF, 0, stream>>>(x, W, nullptr, part, nullptr);
    reduceSquash<0, NCH><<<gR, b256, 0, stream>>>(part, nullptr, vsb, nullptr);
    // pass 2: p = exp(u.v1) -> v2; vs = v1+v2
    fusedK<true, NCH><<<gF, bF, 0, stream>>>(x, W, vsb, part, zpart);
    zredK<NCH><<<dim3(8), b256, 0, stream>>>(zpart, rz);
    reduceSquash<1, NCH><<<gR, b256, 0, stream>>>(part, rz, vsb, nullptr);
    // pass 3: p = exp(u.(v1+v2)) -> v3 = output
    fusedK<true, NCH><<<gF, bF, 0, stream>>>(x, W, vsb, part, zpart);
    zredK<NCH><<<dim3(8), b256, 0, stream>>>(zpart, rz);
    reduceSquash<2, NCH><<<gR, b256, 0, stream>>>(part, rz, nullptr, out);
  };

  const size_t need256 =
      ((size_t)256 * 32768 + 256ul * 2048 + 2048 + 32768) * 4;
  if (ws_size >= need256) run(std::integral_constant<int, 256>{});
  else                    run(std::integral_constant<int, 64>{});
}

// Round 10
// 235.660 us; speedup vs baseline: 1.0016x; 1.0016x over previous
//
#include <hip/hip_runtime.h>
#include <math.h>

#define B_ 64
#define IC 2048
#define OC 32
#define OD 16
#define ID 8

#define GLOAD_LDS16(gp, lp)                                                       \
  __builtin_amdgcn_global_load_lds((const __attribute__((address_space(1))) void*)(gp), \
                                   (__attribute__((address_space(3))) void*)(lp), \
                                   16, 0, 0)

__device__ __forceinline__ float dot8(const float4 w0, const float4 w1,
                                      const float4 xa, const float4 xb) {
  return w0.x*xa.x + w0.y*xa.y + w0.z*xa.z + w0.w*xa.w
       + w1.x*xb.x + w1.y*xb.y + w1.z*xb.z + w1.w*xb.w;
}

// ---------------------------------------------------------------------------
// Fused routing pass (b_k = u.(v1+...+vk) algebra; unnormalized p=exp(u.vs),
// Z applied in reduceSquash).
//
// Geometry (R9, kept): grid = NCH (one block per i-chunk, 1 block/CU at
// NCH=256), block = 512 threads = 8 waves. Wave wv owns b in [wv*8,wv*8+8).
// Lane: op=lane>>2, dq=lane&3; thread owns o in {op, op+16} and d in
// [dq*4, dq*4+4). Per wave-iter: 16 W ds_read_b128 (= W[i] exactly once per
// wave, the LDS-issue minimum for this dataflow) + 16 x broadcast reads for
// 1024 wave-FMAs.
//
// R10 fix: plain __launch_bounds__(512). R9's (512,2) min-arg capped VGPR at
// 128 (CUDA min-blocks semantics: 2 blocks x 8 waves = 16 waves/CU) and the
// ~230-live-VGPR tile spilled to scratch (FETCH 100MB, 78us). The tile needs
// ~240 VGPR -> 2 waves/SIMD, zero spill. NEVER pass the second arg here.
//
// W[i] (16KB) double-buffered via global_load_lds, source XOR-swizzled
// (involution p -> (p&~7)|((p&7)^((p>>3)&7))) so each thread's 8-f4 read
// per o2 spreads across all 32 banks (read index r ^ (lane&7)).
// x window [8 i][64 b][8 m] (16KB) staged once per 8-i subwindow.
// All blocks read disjoint W/x slices: pure streaming.
// ---------------------------------------------------------------------------
template<bool WEIGHTED, int NCH>
__global__ __launch_bounds__(512) void fusedK(
    const float* __restrict__ x, const float* __restrict__ W,
    const float* __restrict__ vs, float* __restrict__ part,
    float* __restrict__ zpart)
{
  constexpr int CI  = IC / NCH;
  constexpr int NSW = CI / 8;
  const int t    = threadIdx.x;
  const int ch   = blockIdx.x;
  const int lane = t & 63;
  const int wv   = t >> 6;
  const int op   = lane >> 2;
  const int dq   = lane & 3;
  const int rot  = lane & 7;
  const int i0   = ch * CI;
  const int b0   = wv * 8;             // wave's first b

  __shared__ float Wbuf[2][4096];      // 2 x 16 KB
  __shared__ float xall[1024 * 4];     // [8 i][64 b][8 m] = 16 KB

  const float4* Wg = (const float4*)W;
  const float4* xg = (const float4*)x;

  float4 acc[2][8];
  float  zacc[2][8];
  float4 vreg[2][8];
#pragma unroll
  for (int o2 = 0; o2 < 2; ++o2)
#pragma unroll
    for (int bb = 0; bb < 8; ++bb) {
      acc[o2][bb] = make_float4(0, 0, 0, 0);
      zacc[o2][bb] = 0.f;
    }

  if constexpr (WEIGHTED) {
#pragma unroll
    for (int o2 = 0; o2 < 2; ++o2)
#pragma unroll
      for (int bb = 0; bb < 8; ++bb)
        vreg[o2][bb] = *(const float4*)(
            vs + ((size_t)(b0 + bb) * 32 + op + o2 * 16) * 16 + dq * 4);
  }

  auto stageW = [&](int i, int nb) {
    const float4* Wi = Wg + (size_t)i * 1024;
#pragma unroll
    for (int k = 0; k < 2; ++k) {
      const int p   = k * 512 + t;
      const int src = (p & ~7) | ((p & 7) ^ ((p >> 3) & 7));
      GLOAD_LDS16(Wi + src, &Wbuf[nb][(k * 512 + wv * 64) * 4]);
    }
  };

  auto stageX = [&](int sw) {
    // xall f4 index p: i = p>>7, b = (p>>1)&63, h = p&1; linear dest
#pragma unroll
    for (int k = 0; k < 2; ++k) {
      const int p = k * 512 + t;
      const int i = p >> 7, b = (p >> 1) & 63, h = p & 1;
      GLOAD_LDS16(xg + ((size_t)b * IC + i0 + sw * 8 + i) * 2 + h,
                  &xall[(k * 512 + wv * 64) * 4]);
    }
  };

  stageX(0);
  stageW(i0, 0);
  int cur = 0;

#pragma unroll 1
  for (int sw = 0; sw < NSW; ++sw) {
#pragma unroll 1
    for (int j = 0; j < 8; ++j) {
      const int ii = sw * 8 + j;

      __syncthreads();                          // drains stage issued last iter
      if (ii + 1 < CI) stageW(i0 + ii + 1, cur ^ 1);

      // Full W fragment for both o-halves: W[i] read exactly once per wave.
      const float* Wb = &Wbuf[cur][0];
      float4 wr[2][8];
#pragma unroll
      for (int o2 = 0; o2 < 2; ++o2) {
        const int jb = (op + o2 * 16) * 32 + dq * 8;
#pragma unroll
        for (int r = 0; r < 8; ++r)
          wr[o2][r] = *(const float4*)&Wb[(jb + (r ^ rot)) * 4];
      }

#pragma unroll
      for (int bb = 0; bb < 8; ++bb) {
        const float* xp = &xall[(j * 128 + (b0 + bb) * 2) * 4];
        const float4 xa = *(const float4*)xp;        // wave-wide broadcast
        const float4 xc = *(const float4*)(xp + 4);  // wave-wide broadcast
#pragma unroll
        for (int o2 = 0; o2 < 2; ++o2) {
          float4 u;
          u.x = dot8(wr[o2][0], wr[o2][1], xa, xc);
          u.y = dot8(wr[o2][2], wr[o2][3], xa, xc);
          u.z = dot8(wr[o2][4], wr[o2][5], xa, xc);
          u.w = dot8(wr[o2][6], wr[o2][7], xa, xc);
          if constexpr (!WEIGHTED) {
            acc[o2][bb].x += u.x; acc[o2][bb].y += u.y;
            acc[o2][bb].z += u.z; acc[o2][bb].w += u.w;
          } else {
            const float4 vv = vreg[o2][bb];
            float pd = u.x * vv.x + u.y * vv.y + u.z * vv.z + u.w * vv.w;
            pd += __shfl_xor(pd, 1);          // reduce over dq (lane bits 0-1)
            pd += __shfl_xor(pd, 2);
            const float p = __expf(pd);       // unnormalized c
            acc[o2][bb].x = fmaf(p, u.x, acc[o2][bb].x);
            acc[o2][bb].y = fmaf(p, u.y, acc[o2][bb].y);
            acc[o2][bb].z = fmaf(p, u.z, acc[o2][bb].z);
            acc[o2][bb].w = fmaf(p, u.w, acc[o2][bb].w);
            zacc[o2][bb] += p;
          }
        }
      }
      cur ^= 1;
    }
    if (sw + 1 < NSW) {
      __syncthreads();              // all waves done reading xall window
      stageX(sw + 1);               // drained by next top-of-iteration barrier
    }
  }

  // epilogue: part[ch][b][o][d] f4-coalesced; zpart[ch][b*32+o] (dq==0)
  float4* part4 = (float4*)part;
#pragma unroll
  for (int o2 = 0; o2 < 2; ++o2)
#pragma unroll
    for (int bb = 0; bb < 8; ++bb) {
      const int b = b0 + bb;
      const int o = op + o2 * 16;
      part4[((size_t)ch * 64 + b) * 128 + o * 4 + dq] = acc[o2][bb];
      if constexpr (WEIGHTED) {
        if (dq == 0) zpart[(size_t)ch * 2048 + b * 32 + o] = zacc[o2][bb];
      }
    }
}

// ---------------------------------------------------------------------------
// Reduce s partials over chunks, normalize, squash.
// PASS 0: s*=1/2048, vs[g]  = v ; PASS 1: s*=rz, vs[g] += v ;
// PASS 2: s*=rz, out[g] = v.   grid 128 x 256; g = b*512 + o*16 + d.
// ---------------------------------------------------------------------------
template<int PASS, int NCH>
__global__ __launch_bounds__(256) void reduceSquash(
    const float* __restrict__ part, const float* __restrict__ rz,
    float* __restrict__ vsio, float* __restrict__ out)
{
  const int g = blockIdx.x * 256 + threadIdx.x;
  float s = 0.f;
#pragma unroll 8
  for (int ch = 0; ch < NCH; ++ch) s += part[(size_t)ch * 32768 + g];
  if constexpr (PASS == 0) s *= (1.f / 2048.f);
  else                     s *= rz[g >> 4];

  float sq = s * s;
#pragma unroll
  for (int k = 1; k < 16; k <<= 1) sq += __shfl_xor(sq, k);   // sum over d
  const float f = (sq / (1.f + sq)) * rsqrtf(sq + 1e-9f);
  const float v = s * f;

  if constexpr (PASS == 0)      vsio[g] = v;
  else if constexpr (PASS == 1) vsio[g] += v;
  else                          out[g] = v;
}

// ---------------------------------------------------------------------------
// Z reduction: rz[b*32+o] = 1 / sum_ch zpart. grid 8 x 256.
// ---------------------------------------------------------------------------
template<int NCH>
__global__ __launch_bounds__(256) void zredK(
    const float* __restrict__ zpart, float* __restrict__ rz)
{
  const int j = blockIdx.x * 256 + threadIdx.x;
  float zs = 0.f;
#pragma unroll 8
  for (int ch = 0; ch < NCH; ++ch) zs += zpart[(size_t)ch * 2048 + j];
  rz[j] = 1.f / zs;
}

// ---------------------------------------------------------------------------
extern "C" void kernel_launch(void* const* d_in, const int* in_sizes, int n_in,
                              void* d_out, int out_size, void* d_ws, size_t ws_size,
                              hipStream_t stream) {
  (void)in_sizes; (void)n_in; (void)out_size;
  const float* x = (const float*)d_in[0];
  const float* W = (const float*)d_in[1];
  float* out = (float*)d_out;
  float* ws  = (float*)d_ws;

  auto run = [&](auto tag) {
    constexpr int NCH = decltype(tag)::value;
    float* part  = ws;                                 // [NCH][64][32][16]
    float* zpart = part + (size_t)NCH * 32768;         // [NCH][2048]
    float* rz    = zpart + (size_t)NCH * 2048;         // [2048]
    float* vsb   = rz + 2048;                          // vs running sum [32768]

    const dim3 gF(NCH), bF(512), b256(256), gR(128);
    // pass 1: uniform c -> v1 (vs = v1)
    fusedK<false, NCH><<<gF, bF, 0, stream>>>(x, W, nullptr, part, nullptr);
    reduceSquash<0, NCH><<<gR, b256, 0, stream>>>(part, nullptr, vsb, nullptr);
    // pass 2: p = exp(u.v1) -> v2; vs = v1+v2
    fusedK<true, NCH><<<gF, bF, 0, stream>>>(x, W, vsb, part, zpart);
    zredK<NCH><<<dim3(8), b256, 0, stream>>>(zpart, rz);
    reduceSquash<1, NCH><<<gR, b256, 0, stream>>>(part, rz, vsb, nullptr);
    // pass 3: p = exp(u.(v1+v2)) -> v3 = output
    fusedK<true, NCH><<<gF, bF, 0, stream>>>(x, W, vsb, part, zpart);
    zredK<NCH><<<dim3(8), b256, 0, stream>>>(zpart, rz);
    reduceSquash<2, NCH><<<gR, b256, 0, stream>>>(part, rz, nullptr, out);
  };

  const size_t need256 =
      ((size_t)256 * 32768 + 256ul * 2048 + 2048 + 32768) * 4;
  if (ws_size >= need256) run(std::integral_constant<int, 256>{});
  else                    run(std::integral_constant<int, 64>{});
}